// Round 2
// baseline (106.841 us; speedup 1.0000x reference)
//
#include <hip/hip_runtime.h>
#include <hip/hip_bf16.h>

// out[b,u] = tanh( sum_f inputs[b, T-1, f] * kernel[f,u] + bias[u] )
// B=256, T=512, F=256, U=256, fp32.
//
// Grid: 256 blocks x 64 threads (1 wave). Block (blk) covers a 4b x 64u tile:
//   b0 = (blk & 63)*4, u0 = (blk >> 6)*64.
// Lane covers 1 b-row x 4 u-cols: b = b0 + (lane>>4), u = u0 + (lane&15)*4.
//   -> kernel loads are float4; 4 lanes share each float4 (coalescer merges,
//      256 B unique per wave per f-row); per-CU unique kernel bytes = 64 KB
//      (vs 256 KB in round 1 -> 4x less L2 traffic).
// Double-buffered prefetch of UN=32 f-rows keeps 32 float4 loads (8 KB/wave)
// in flight, hiding L2 latency under the 128-FMA batches. acc.x/y/z/w give
// 4 independent FMA chains.

#define B_DIM 256
#define T_DIM 512
#define F_DIM 256
#define U_DIM 256
#define UN 32
#define NBATCH (F_DIM / UN)   // 8

__global__ __launch_bounds__(64, 1) void lastslice_matmul_tanh(
    const float* __restrict__ inputs,   // [B, T, F]
    const float* __restrict__ kern,     // [F, U]
    const float* __restrict__ bias,     // [U]
    float* __restrict__ out)            // [B, U]
{
    const int lane = threadIdx.x;          // 0..63
    const int blk  = blockIdx.x;           // 0..255
    const int b0   = (blk & 63) * 4;
    const int u0   = (blk >> 6) * 64;
    const int bhat = lane >> 4;            // 0..3
    const int uoff = (lane & 15) * 4;      // 0..60

    __shared__ __align__(16) float xs[4][F_DIM];   // 4 KB

    const float* kcol = kern + u0 + uoff;

    // Issue first kernel batch ASAP (overlaps with x staging).
    float4 bufA[UN], bufB[UN];
    #pragma unroll
    for (int i = 0; i < UN; ++i)
        bufA[i] = *(const float4*)(kcol + (size_t)i * U_DIM);

    // Stage the 4 last-timestep x-rows into LDS (1024 floats = 4 float4/lane).
    #pragma unroll
    for (int i = 0; i < 4; ++i) {
        int idx = lane + 64 * i;           // float4 index over [4][64]
        int r = idx >> 6, c = idx & 63;
        const float4* src = (const float4*)(inputs +
            ((size_t)(b0 + r) * T_DIM + (T_DIM - 1)) * F_DIM);
        ((float4*)&xs[r][0])[c] = src[c];
    }
    __syncthreads();   // single wave: cheap; orders LDS writes vs reads

    float4 acc = *(const float4*)(bias + u0 + uoff);

    #pragma unroll
    for (int t = 0; t < NBATCH; ++t) {
        float4* cur = (t & 1) ? bufB : bufA;
        float4* nxt = (t & 1) ? bufA : bufB;

        // Prefetch next batch of 32 f-rows (skip on last iteration).
        if (t < NBATCH - 1) {
            #pragma unroll
            for (int i = 0; i < UN; ++i) {
                int fr = (t + 1) * UN + i;
                nxt[i] = *(const float4*)(kcol + (size_t)fr * U_DIM);
            }
        }

        // FMA current batch from registers; x read as float4 from LDS.
        #pragma unroll
        for (int i = 0; i < UN; i += 4) {
            const float4 xq = ((const float4*)&xs[bhat][0])[(t * UN + i) >> 2];
            const float xv[4] = {xq.x, xq.y, xq.z, xq.w};
            #pragma unroll
            for (int j = 0; j < 4; ++j) {
                acc.x = fmaf(xv[j], cur[i + j].x, acc.x);
                acc.y = fmaf(xv[j], cur[i + j].y, acc.y);
                acc.z = fmaf(xv[j], cur[i + j].z, acc.z);
                acc.w = fmaf(xv[j], cur[i + j].w, acc.w);
            }
        }
    }

    float4 r;
    r.x = tanhf(acc.x);
    r.y = tanhf(acc.y);
    r.z = tanhf(acc.z);
    r.w = tanhf(acc.w);
    *(float4*)(out + (size_t)(b0 + bhat) * U_DIM + u0 + uoff) = r;
}

extern "C" void kernel_launch(void* const* d_in, const int* in_sizes, int n_in,
                              void* d_out, int out_size, void* d_ws, size_t ws_size,
                              hipStream_t stream) {
    const float* inputs = (const float*)d_in[0];   // B*T*F
    const float* kern   = (const float*)d_in[1];   // F*U
    const float* bias   = (const float*)d_in[2];   // U
    float* out          = (float*)d_out;           // B*U

    dim3 grid(256);
    dim3 block(64);
    lastslice_matmul_tanh<<<grid, block, 0, stream>>>(inputs, kern, bias, out);
}

// Round 3
// 9.601 us; speedup vs baseline: 11.1276x; 11.1276x over previous
//
#include <hip/hip_runtime.h>
#include <hip/hip_bf16.h>

// out[b,u] = tanh( sum_f inputs[b, T-1, f] * kernel[f,u] + bias[u] )
// B=256, T=512, F=256, U=256, fp32.
//
// Grid: 256 blocks (one per b) x 256 threads (4 waves).
// Wave w handles f-rows [w*64, w*64+64); lane covers u = lane*4 .. lane*4+3
// (float4 kernel loads, fully coalesced: 1 KB per wave per f-row).
// Per wave: 4 batches of 16 float4 loads, double-buffered (16+16 = 128 VGPRs
// in flight -- deliberately HALF of round 2's 256-VGPR spill disaster).
// Waves' partials combine via 4 KB LDS + one __syncthreads, then bias+tanh.

#define T_DIM 512
#define F_DIM 256
#define U_DIM 256

__global__ __launch_bounds__(256) void lastslice_matmul_tanh(
    const float* __restrict__ inputs,   // [B, T, F]
    const float* __restrict__ kern,     // [F, U]
    const float* __restrict__ bias,     // [U]
    float* __restrict__ out)            // [B, U]
{
    const int tid  = threadIdx.x;
    const int lane = tid & 63;
    const int w    = tid >> 6;          // wave id 0..3 -> f-chunk
    const int b    = blockIdx.x;
    const int u0   = lane * 4;

    __shared__ __align__(16) float xs[4][64];     // wave-private x chunks
    __shared__ __align__(16) float part[4][U_DIM];

    // Stage this wave's 64 x-values (same-wave LDS RAW: no barrier needed).
    const float* xrow = inputs + ((size_t)b * T_DIM + (T_DIM - 1)) * F_DIM;
    xs[w][lane] = xrow[w * 64 + lane];

    const float* kbase = kern + (size_t)(w * 64) * U_DIM + u0;

    // Batch 0 into A.
    float4 A[16], Bb[16];
    #pragma unroll
    for (int j = 0; j < 16; ++j)
        A[j] = *(const float4*)(kbase + (size_t)j * U_DIM);

    float4 acc = make_float4(0.f, 0.f, 0.f, 0.f);

    #pragma unroll
    for (int t = 0; t < 4; ++t) {
        // Prefetch next batch into the other buffer (static after unroll).
        if (t < 3) {
            #pragma unroll
            for (int j = 0; j < 16; ++j)
                ((t & 1) ? A : Bb)[j] =
                    *(const float4*)(kbase + (size_t)((t + 1) * 16 + j) * U_DIM);
        }
        const float4* cur = (t & 1) ? Bb : A;
        #pragma unroll
        for (int j4 = 0; j4 < 4; ++j4) {
            const float4 xq = ((const float4*)&xs[w][0])[t * 4 + j4];
            const float xv[4] = {xq.x, xq.y, xq.z, xq.w};
            #pragma unroll
            for (int jj = 0; jj < 4; ++jj) {
                const float4 kv = cur[j4 * 4 + jj];
                acc.x = fmaf(xv[jj], kv.x, acc.x);
                acc.y = fmaf(xv[jj], kv.y, acc.y);
                acc.z = fmaf(xv[jj], kv.z, acc.z);
                acc.w = fmaf(xv[jj], kv.w, acc.w);
            }
        }
    }

    // Combine the 4 waves' partials.
    *(float4*)&part[w][u0] = acc;
    __syncthreads();

    const int u = tid;                  // 0..255
    float s = part[0][u] + part[1][u] + part[2][u] + part[3][u] + bias[u];
    out[(size_t)b * U_DIM + u] = tanhf(s);
}

extern "C" void kernel_launch(void* const* d_in, const int* in_sizes, int n_in,
                              void* d_out, int out_size, void* d_ws, size_t ws_size,
                              hipStream_t stream) {
    const float* inputs = (const float*)d_in[0];   // B*T*F
    const float* kern   = (const float*)d_in[1];   // F*U
    const float* bias   = (const float*)d_in[2];   // U
    float* out          = (float*)d_out;           // B*U

    dim3 grid(256);
    dim3 block(256);
    lastslice_matmul_tanh<<<grid, block, 0, stream>>>(inputs, kern, bias, out);
}